// Round 1
// baseline (945.974 us; speedup 1.0000x reference)
//
#include <hip/hip_runtime.h>

#define D 64

__global__ void set_deg(float* __restrict__ deg, int n, float fill) {
    int i = blockIdx.x * blockDim.x + threadIdx.x;
    if (i < n) deg[i] = fill;
}

__global__ void accum_deg(const int* __restrict__ row, const float* __restrict__ w,
                          float* __restrict__ deg, int E) {
    int e = blockIdx.x * blockDim.x + threadIdx.x;
    if (e < E) atomicAdd(&deg[row[e]], w[e]);
}

__global__ void finalize_dinv(float* __restrict__ deg, int n) {
    int i = blockIdx.x * blockDim.x + threadIdx.x;
    if (i < n) {
        float d = deg[i];
        deg[i] = d > 0.0f ? rsqrtf(d) : 0.0f;
    }
}

// h_out[i,:] = h_in[i,:] * dinv[i]^2   (self-loop message, fill=1.0; also inits buffer)
__global__ void hop_init(const float* __restrict__ h_in, const float* __restrict__ dinv,
                         float* __restrict__ h_out, int n) {
    int t = blockIdx.x * blockDim.x + threadIdx.x;
    int i = t >> 6;
    if (i < n) {
        float di = dinv[i];
        h_out[t] = h_in[t] * (di * di);
    }
}

// per-(edge, column) scatter: h_out[row,j] += h_in[col,j] * dinv[row]*w*dinv[col]
__global__ void hop_edges(const int* __restrict__ row, const int* __restrict__ col,
                          const float* __restrict__ w, const float* __restrict__ dinv,
                          const float* __restrict__ h_in, float* __restrict__ h_out,
                          int E) {
    long t = (long)blockIdx.x * blockDim.x + threadIdx.x;
    int e = (int)(t >> 6);
    int j = (int)(t & 63);
    if (e >= E) return;
    int r = row[e];
    int c = col[e];
    float nw = dinv[r] * w[e] * dinv[c];
    atomicAdd(&h_out[(long)r * D + j], h_in[(long)c * D + j] * nw);
}

// in-place projection: out[i,:] = out[i,:] @ W + bias. One wave per row.
__global__ void proj_inplace(float* __restrict__ h, const float* __restrict__ W,
                             const float* __restrict__ bias, int n) {
    __shared__ float Wl[D * D];
    __shared__ float bl[D];
    int tid = threadIdx.x;
    for (int k = tid; k < D * D; k += blockDim.x) Wl[k] = W[k];
    if (tid < D) bl[tid] = bias[tid];
    __syncthreads();

    int lane = tid & 63;
    int wave = tid >> 6;
    int wavesPerBlock = blockDim.x >> 6;
    long nWaves = (long)gridDim.x * wavesPerBlock;
    for (long r = (long)blockIdx.x * wavesPerBlock + wave; r < n; r += nWaves) {
        float hv = h[r * D + lane];
        float y = bl[lane];
        #pragma unroll
        for (int k = 0; k < D; ++k) {
            y += __shfl(hv, k, 64) * Wl[k * D + lane];
        }
        h[r * D + lane] = y;
    }
}

extern "C" void kernel_launch(void* const* d_in, const int* in_sizes, int n_in,
                              void* d_out, int out_size, void* d_ws, size_t ws_size,
                              hipStream_t stream) {
    const float* x    = (const float*)d_in[0];
    const int*   ei   = (const int*)d_in[1];
    const float* ew   = (const float*)d_in[2];
    const float* W    = (const float*)d_in[3];
    const float* bias = (const float*)d_in[4];

    int n = in_sizes[0] / D;     // 100000
    int E = in_sizes[2];         // 1600000
    const int* row = ei;         // targets (scatter dst)
    const int* col = ei + E;     // sources (gather src)

    float* out = (float*)d_out;

    // workspace layout: deg/dinv [n], h1 [n*D]
    float* deg = (float*)d_ws;
    float* h1  = deg + ((n + 255) & ~255);

    const float fill = 1.0f;  // IMPROVED = False

    int blk = 256;
    // degree + normalization
    set_deg<<<(n + blk - 1) / blk, blk, 0, stream>>>(deg, n, fill);
    accum_deg<<<(E + blk - 1) / blk, blk, 0, stream>>>(row, ew, deg, E);
    finalize_dinv<<<(n + blk - 1) / blk, blk, 0, stream>>>(deg, n);

    long nThreadsNode = (long)n * D;
    long nThreadsEdge = (long)E * D;

    // hop 1: x -> h1
    hop_init<<<(int)((nThreadsNode + blk - 1) / blk), blk, 0, stream>>>(x, deg, h1, n);
    hop_edges<<<(int)((nThreadsEdge + blk - 1) / blk), blk, 0, stream>>>(row, col, ew, deg, x, h1, E);

    // hop 2: h1 -> out
    hop_init<<<(int)((nThreadsNode + blk - 1) / blk), blk, 0, stream>>>(h1, deg, out, n);
    hop_edges<<<(int)((nThreadsEdge + blk - 1) / blk), blk, 0, stream>>>(row, col, ew, deg, h1, out, E);

    // projection in-place on out
    proj_inplace<<<(n + 3) / 4, blk, 0, stream>>>(out, W, bias, n);
}

// Round 2
// 630.732 us; speedup vs baseline: 1.4998x; 1.4998x over previous
//
#include <hip/hip_runtime.h>

#define D 64

static __host__ __device__ inline int alignup(int x) { return (x + 63) & ~63; }

// wdeg[i] = fill (self-loop weight), cnt[i] = 0
__global__ void init_deg_cnt(float* __restrict__ wdeg, int* __restrict__ cnt, int n, float fill) {
    int i = blockIdx.x * blockDim.x + threadIdx.x;
    if (i < n) { wdeg[i] = fill; cnt[i] = 0; }
}

// histogram: weighted degree (for dinv) + edge count per row (for CSR)
__global__ void accum_deg_cnt(const int* __restrict__ row, const float* __restrict__ w,
                              float* __restrict__ wdeg, int* __restrict__ cnt, int E) {
    int e = blockIdx.x * blockDim.x + threadIdx.x;
    if (e < E) {
        int r = row[e];
        atomicAdd(&wdeg[r], w[e]);
        atomicAdd(&cnt[r], 1);
    }
}

__global__ void finalize_dinv(float* __restrict__ wdeg, int n) {
    int i = blockIdx.x * blockDim.x + threadIdx.x;
    if (i < n) {
        float d = wdeg[i];
        wdeg[i] = d > 0.0f ? rsqrtf(d) : 0.0f;
    }
}

// scan step 1: per-block (256) sums of cnt
__global__ void scan_block_sums(const int* __restrict__ cnt, int* __restrict__ bsums, int n) {
    __shared__ int s[256];
    int t = threadIdx.x;
    int i = blockIdx.x * 256 + t;
    s[t] = (i < n) ? cnt[i] : 0;
    __syncthreads();
    for (int st = 128; st > 0; st >>= 1) {
        if (t < st) s[t] += s[t + st];
        __syncthreads();
    }
    if (t == 0) bsums[blockIdx.x] = s[0];
}

// scan step 2: single-block exclusive scan of block sums (nb <= 1024)
__global__ void scan_bsums(int* __restrict__ bsums, int nb) {
    __shared__ int s[1024];
    int t = threadIdx.x;
    s[t] = (t < nb) ? bsums[t] : 0;
    __syncthreads();
    for (int off = 1; off < 1024; off <<= 1) {
        int v = 0;
        if (t >= off) v = s[t - off];
        __syncthreads();
        if (t >= off) s[t] += v;
        __syncthreads();
    }
    // s is inclusive; write exclusive
    if (t < nb) bsums[t] = (t == 0) ? 0 : s[t - 1];
}

// scan step 3: per-block exclusive scan + block prefix -> off, cur
__global__ void scan_final(const int* __restrict__ cnt, const int* __restrict__ bsums,
                           int* __restrict__ off, int* __restrict__ cur, int n) {
    __shared__ int s[256];
    int t = threadIdx.x;
    int i = blockIdx.x * 256 + t;
    int v = (i < n) ? cnt[i] : 0;
    s[t] = v;
    __syncthreads();
    for (int o = 1; o < 256; o <<= 1) {
        int u = 0;
        if (t >= o) u = s[t - o];
        __syncthreads();
        if (t >= o) s[t] += u;
        __syncthreads();
    }
    if (i < n) {
        int o0 = bsums[blockIdx.x] + s[t] - v;  // exclusive prefix
        off[i] = o0;
        cur[i] = o0;
    }
}

// scatter edges into CSR slots; store pre-normalized weight dinv[r]*w*dinv[c]
__global__ void scatter_csr(const int* __restrict__ row, const int* __restrict__ col,
                            const float* __restrict__ w, const float* __restrict__ dinv,
                            int* __restrict__ cur, int* __restrict__ csr_col,
                            float* __restrict__ csr_w, int E) {
    int e = blockIdx.x * blockDim.x + threadIdx.x;
    if (e >= E) return;
    int r = row[e];
    int c = col[e];
    int pos = atomicAdd(&cur[r], 1);
    csr_col[pos] = c;
    csr_w[pos] = dinv[r] * w[e] * dinv[c];
}
// after scatter_csr: cur[r] == segment end for node r

// hop (gather form): one wave per node, lane j owns column j.
__global__ void hop_gather(const float* __restrict__ h_in, const float* __restrict__ dinv,
                           const int* __restrict__ off, const int* __restrict__ end,
                           const int* __restrict__ csr_col, const float* __restrict__ csr_w,
                           float* __restrict__ h_out, int n) {
    int t = blockIdx.x * blockDim.x + threadIdx.x;
    int i = t >> 6;
    int lane = t & 63;
    if (i >= n) return;
    float di = dinv[i];
    float acc = h_in[(long)i * D + lane] * (di * di);  // self-loop (fill=1)
    int s = off[i], e = end[i];
    for (int p = s; p < e; ++p) {
        int c = csr_col[p];
        float wv = csr_w[p];
        acc += h_in[(long)c * D + lane] * wv;
    }
    h_out[(long)i * D + lane] = acc;
}

// hop 2 fused with projection: out[i,:] = h2[i,:] @ W + bias
__global__ void hop_gather_proj(const float* __restrict__ h_in, const float* __restrict__ dinv,
                                const int* __restrict__ off, const int* __restrict__ end,
                                const int* __restrict__ csr_col, const float* __restrict__ csr_w,
                                const float* __restrict__ W, const float* __restrict__ bias,
                                float* __restrict__ out, int n) {
    __shared__ float Wl[D * D];
    __shared__ float bl[D];
    for (int k = threadIdx.x; k < D * D; k += blockDim.x) Wl[k] = W[k];
    if (threadIdx.x < D) bl[threadIdx.x] = bias[threadIdx.x];
    __syncthreads();

    int t = blockIdx.x * blockDim.x + threadIdx.x;
    int i = t >> 6;
    int lane = t & 63;
    if (i >= n) return;  // wave-uniform (all 64 lanes share i)

    float di = dinv[i];
    float acc = h_in[(long)i * D + lane] * (di * di);
    int s = off[i], e = end[i];
    for (int p = s; p < e; ++p) {
        acc += h_in[(long)csr_col[p] * D + lane] * csr_w[p];
    }
    // project: lane holds h2[i,lane]; y_l = bias_l + sum_k h2[i,k] * W[k,l]
    float y = bl[lane];
    #pragma unroll
    for (int k = 0; k < D; ++k) {
        y += __shfl(acc, k, 64) * Wl[k * D + lane];
    }
    out[(long)i * D + lane] = y;
}

extern "C" void kernel_launch(void* const* d_in, const int* in_sizes, int n_in,
                              void* d_out, int out_size, void* d_ws, size_t ws_size,
                              hipStream_t stream) {
    const float* x    = (const float*)d_in[0];
    const int*   ei   = (const int*)d_in[1];
    const float* ew   = (const float*)d_in[2];
    const float* W    = (const float*)d_in[3];
    const float* bias = (const float*)d_in[4];

    int n = in_sizes[0] / D;   // 100000
    int E = in_sizes[2];       // 1600000
    const int* row = ei;       // scatter targets
    const int* col = ei + E;   // gather sources

    float* out = (float*)d_out;

    // workspace layout
    float* wdeg    = (float*)d_ws;               // n   (becomes dinv)
    int*   cnt     = (int*)(wdeg + alignup(n));  // n
    int*   bsums   = cnt + alignup(n);           // <=1024
    int*   off     = bsums + 1024;               // n
    int*   cur     = off + alignup(n);           // n   (becomes segment end)
    int*   csr_col = cur + alignup(n);           // E
    float* csr_w   = (float*)(csr_col + alignup(E)); // E
    float* h1      = csr_w + alignup(E);         // n*D

    const float fill = 1.0f;  // IMPROVED = False
    const int blk = 256;
    int nbN = (n + blk - 1) / blk;   // 391
    int nbE = (E + blk - 1) / blk;

    // degree + CSR counts
    init_deg_cnt<<<nbN, blk, 0, stream>>>(wdeg, cnt, n, fill);
    accum_deg_cnt<<<nbE, blk, 0, stream>>>(row, ew, wdeg, cnt, E);
    finalize_dinv<<<nbN, blk, 0, stream>>>(wdeg, n);

    // exclusive scan of cnt -> off (3-kernel block scan; nbN <= 1024)
    scan_block_sums<<<nbN, blk, 0, stream>>>(cnt, bsums, n);
    scan_bsums<<<1, 1024, 0, stream>>>(bsums, nbN);
    scan_final<<<nbN, blk, 0, stream>>>(cnt, bsums, off, cur, n);

    // CSR scatter with pre-normalized weights
    scatter_csr<<<nbE, blk, 0, stream>>>(row, col, ew, wdeg, cur, csr_col, csr_w, E);

    // hops (gather form), projection fused into hop 2
    int nbWave = (int)(((long)n * D + blk - 1) / blk);  // one wave per node
    hop_gather<<<nbWave, blk, 0, stream>>>(x, wdeg, off, cur, csr_col, csr_w, h1, n);
    hop_gather_proj<<<nbWave, blk, 0, stream>>>(h1, wdeg, off, cur, csr_col, csr_w,
                                                W, bias, out, n);
}

// Round 3
// 469.362 us; speedup vs baseline: 2.0154x; 1.3438x over previous
//
#include <hip/hip_runtime.h>

#define D 64

static __host__ __device__ inline int alignup(int x) { return (x + 63) & ~63; }

__global__ void init_deg_cnt(float* __restrict__ wdeg, int* __restrict__ cnt, int n, float fill) {
    int i = blockIdx.x * blockDim.x + threadIdx.x;
    if (i < n) { wdeg[i] = fill; cnt[i] = 0; }
}

__global__ void accum_deg_cnt(const int* __restrict__ row, const float* __restrict__ w,
                              float* __restrict__ wdeg, int* __restrict__ cnt, int E) {
    int e = blockIdx.x * blockDim.x + threadIdx.x;
    if (e < E) {
        int r = row[e];
        atomicAdd(&wdeg[r], w[e]);
        atomicAdd(&cnt[r], 1);
    }
}

__global__ void finalize_dinv(float* __restrict__ wdeg, int n) {
    int i = blockIdx.x * blockDim.x + threadIdx.x;
    if (i < n) {
        float d = wdeg[i];
        wdeg[i] = d > 0.0f ? rsqrtf(d) : 0.0f;
    }
}

__global__ void scan_block_sums(const int* __restrict__ cnt, int* __restrict__ bsums, int n) {
    __shared__ int s[256];
    int t = threadIdx.x;
    int i = blockIdx.x * 256 + t;
    s[t] = (i < n) ? cnt[i] : 0;
    __syncthreads();
    for (int st = 128; st > 0; st >>= 1) {
        if (t < st) s[t] += s[t + st];
        __syncthreads();
    }
    if (t == 0) bsums[blockIdx.x] = s[0];
}

__global__ void scan_bsums(int* __restrict__ bsums, int nb) {
    __shared__ int s[1024];
    int t = threadIdx.x;
    s[t] = (t < nb) ? bsums[t] : 0;
    __syncthreads();
    for (int off = 1; off < 1024; off <<= 1) {
        int v = 0;
        if (t >= off) v = s[t - off];
        __syncthreads();
        if (t >= off) s[t] += v;
        __syncthreads();
    }
    if (t < nb) bsums[t] = (t == 0) ? 0 : s[t - 1];
}

__global__ void scan_final(const int* __restrict__ cnt, const int* __restrict__ bsums,
                           int* __restrict__ off, int* __restrict__ cur, int n) {
    __shared__ int s[256];
    int t = threadIdx.x;
    int i = blockIdx.x * 256 + t;
    int v = (i < n) ? cnt[i] : 0;
    s[t] = v;
    __syncthreads();
    for (int o = 1; o < 256; o <<= 1) {
        int u = 0;
        if (t >= o) u = s[t - o];
        __syncthreads();
        if (t >= o) s[t] += u;
        __syncthreads();
    }
    if (i < n) {
        int o0 = bsums[blockIdx.x] + s[t] - v;
        off[i] = o0;
        cur[i] = o0;
    }
}

__global__ void scatter_csr(const int* __restrict__ row, const int* __restrict__ col,
                            const float* __restrict__ w, const float* __restrict__ dinv,
                            int* __restrict__ cur, int* __restrict__ csr_col,
                            float* __restrict__ csr_w, int E) {
    int e = blockIdx.x * blockDim.x + threadIdx.x;
    if (e >= E) return;
    int r = row[e];
    int c = col[e];
    int pos = atomicAdd(&cur[r], 1);
    csr_col[pos] = c;
    csr_w[pos] = dinv[r] * w[e] * dinv[c];
}

// hop, gather form with max MLP: one wave per node. Whole segment's indices
// loaded in one coalesced 64-lane load, broadcast via shfl, 4 independent
// accumulator chains so gathers stay many-deep in flight.
__global__ void hop_gather(const float* __restrict__ h_in, const float* __restrict__ dinv,
                           const int* __restrict__ off, const int* __restrict__ end,
                           const int* __restrict__ csr_col, const float* __restrict__ csr_w,
                           float* __restrict__ h_out, int n) {
    int t = blockIdx.x * blockDim.x + threadIdx.x;
    int i = t >> 6;
    int lane = t & 63;
    if (i >= n) return;
    float di = dinv[i];
    float a0 = h_in[(long)i * D + lane] * (di * di);  // self-loop (fill=1)
    float a1 = 0.f, a2 = 0.f, a3 = 0.f;
    int s = off[i], e = end[i];
    for (int base = s; base < e; base += 64) {
        int m = e - base; if (m > 64) m = 64;
        int idx = base + (lane < m ? lane : m - 1);
        int cols = csr_col[idx];
        float ws  = csr_w[idx];
        int p = 0;
        for (; p + 4 <= m; p += 4) {
            int   c0 = __shfl(cols, p, 64),   c1 = __shfl(cols, p+1, 64);
            int   c2 = __shfl(cols, p+2, 64), c3 = __shfl(cols, p+3, 64);
            float w0 = __shfl(ws, p, 64),     w1 = __shfl(ws, p+1, 64);
            float w2 = __shfl(ws, p+2, 64),   w3 = __shfl(ws, p+3, 64);
            a0 += h_in[(long)c0 * D + lane] * w0;
            a1 += h_in[(long)c1 * D + lane] * w1;
            a2 += h_in[(long)c2 * D + lane] * w2;
            a3 += h_in[(long)c3 * D + lane] * w3;
        }
        for (; p < m; ++p) {
            int c = __shfl(cols, p, 64);
            float wv = __shfl(ws, p, 64);
            a0 += h_in[(long)c * D + lane] * wv;
        }
    }
    h_out[(long)i * D + lane] = (a0 + a1) + (a2 + a3);
}

// hop 2 fused with projection
__global__ void hop_gather_proj(const float* __restrict__ h_in, const float* __restrict__ dinv,
                                const int* __restrict__ off, const int* __restrict__ end,
                                const int* __restrict__ csr_col, const float* __restrict__ csr_w,
                                const float* __restrict__ W, const float* __restrict__ bias,
                                float* __restrict__ out, int n) {
    __shared__ float Wl[D * D];
    __shared__ float bl[D];
    for (int k = threadIdx.x; k < D * D; k += blockDim.x) Wl[k] = W[k];
    if (threadIdx.x < D) bl[threadIdx.x] = bias[threadIdx.x];
    __syncthreads();

    int t = blockIdx.x * blockDim.x + threadIdx.x;
    int i = t >> 6;
    int lane = t & 63;
    if (i >= n) return;

    float di = dinv[i];
    float a0 = h_in[(long)i * D + lane] * (di * di);
    float a1 = 0.f, a2 = 0.f, a3 = 0.f;
    int s = off[i], e = end[i];
    for (int base = s; base < e; base += 64) {
        int m = e - base; if (m > 64) m = 64;
        int idx = base + (lane < m ? lane : m - 1);
        int cols = csr_col[idx];
        float ws  = csr_w[idx];
        int p = 0;
        for (; p + 4 <= m; p += 4) {
            int   c0 = __shfl(cols, p, 64),   c1 = __shfl(cols, p+1, 64);
            int   c2 = __shfl(cols, p+2, 64), c3 = __shfl(cols, p+3, 64);
            float w0 = __shfl(ws, p, 64),     w1 = __shfl(ws, p+1, 64);
            float w2 = __shfl(ws, p+2, 64),   w3 = __shfl(ws, p+3, 64);
            a0 += h_in[(long)c0 * D + lane] * w0;
            a1 += h_in[(long)c1 * D + lane] * w1;
            a2 += h_in[(long)c2 * D + lane] * w2;
            a3 += h_in[(long)c3 * D + lane] * w3;
        }
        for (; p < m; ++p) {
            int c = __shfl(cols, p, 64);
            float wv = __shfl(ws, p, 64);
            a0 += h_in[(long)c * D + lane] * wv;
        }
    }
    float acc = (a0 + a1) + (a2 + a3);

    float y = bl[lane];
    #pragma unroll
    for (int k = 0; k < D; ++k) {
        y += __shfl(acc, k, 64) * Wl[k * D + lane];
    }
    out[(long)i * D + lane] = y;
}

extern "C" void kernel_launch(void* const* d_in, const int* in_sizes, int n_in,
                              void* d_out, int out_size, void* d_ws, size_t ws_size,
                              hipStream_t stream) {
    const float* x    = (const float*)d_in[0];
    const int*   ei   = (const int*)d_in[1];
    const float* ew   = (const float*)d_in[2];
    const float* W    = (const float*)d_in[3];
    const float* bias = (const float*)d_in[4];

    int n = in_sizes[0] / D;   // 100000
    int E = in_sizes[2];       // 1600000
    const int* row = ei;
    const int* col = ei + E;

    float* out = (float*)d_out;

    float* wdeg    = (float*)d_ws;               // n (becomes dinv)
    int*   cnt     = (int*)(wdeg + alignup(n));  // n
    int*   bsums   = cnt + alignup(n);           // <=1024
    int*   off     = bsums + 1024;               // n
    int*   cur     = off + alignup(n);           // n (becomes segment end)
    int*   csr_col = cur + alignup(n);           // E
    float* csr_w   = (float*)(csr_col + alignup(E)); // E
    float* h1      = csr_w + alignup(E);         // n*D

    const float fill = 1.0f;  // IMPROVED = False
    const int blk = 256;
    int nbN = (n + blk - 1) / blk;
    int nbE = (E + blk - 1) / blk;

    init_deg_cnt<<<nbN, blk, 0, stream>>>(wdeg, cnt, n, fill);
    accum_deg_cnt<<<nbE, blk, 0, stream>>>(row, ew, wdeg, cnt, E);
    finalize_dinv<<<nbN, blk, 0, stream>>>(wdeg, n);

    scan_block_sums<<<nbN, blk, 0, stream>>>(cnt, bsums, n);
    scan_bsums<<<1, 1024, 0, stream>>>(bsums, nbN);
    scan_final<<<nbN, blk, 0, stream>>>(cnt, bsums, off, cur, n);

    scatter_csr<<<nbE, blk, 0, stream>>>(row, col, ew, wdeg, cur, csr_col, csr_w, E);

    int nbWave = (int)(((long)n * D + blk - 1) / blk);
    hop_gather<<<nbWave, blk, 0, stream>>>(x, wdeg, off, cur, csr_col, csr_w, h1, n);
    hop_gather_proj<<<nbWave, blk, 0, stream>>>(h1, wdeg, off, cur, csr_col, csr_w,
                                                W, bias, out, n);
}